// Round 9
// baseline (293.377 us; speedup 1.0000x reference)
//
#include <hip/hip_runtime.h>
#include <hip/hip_bf16.h>
#include <cstdint>
#include <cstddef>

#define NN 8192
#define EE 262144
#define IN_F 256
#define HID_F 128
#define OUT_F 64

typedef __attribute__((ext_vector_type(8))) short short8v;
typedef __attribute__((ext_vector_type(4))) float f32x4;
typedef __attribute__((ext_vector_type(4))) unsigned short ushort4v;

// bf16 round-to-nearest-even split helpers
static __device__ __forceinline__ unsigned short f2bf(float x) {
    unsigned int u = __float_as_uint(x);
    unsigned int r = (u + 0x7fffu + ((u >> 16) & 1u)) >> 16;
    return (unsigned short)r;
}
static __device__ __forceinline__ float bf2f(unsigned short u) {
    return __uint_as_float(((unsigned int)u) << 16);
}

// ---------- prep: rowptr (binary search on sorted src) + norm + weight conversion ----------
__global__ void k_prep(const int* __restrict__ src,
                       const float* __restrict__ W0, const float* __restrict__ Wmu,
                       const float* __restrict__ Wls,
                       int* __restrict__ rp, float* __restrict__ norm,
                       unsigned short* __restrict__ W0h, unsigned short* __restrict__ W0l,
                       unsigned short* __restrict__ Wch, unsigned short* __restrict__ Wcl) {
    int i = blockIdx.x * blockDim.x + threadIdx.x;
    if (i <= NN) {
        auto lb = [&](int key) {
            int lo = 0, hi = EE;
            while (lo < hi) { int mid = (lo + hi) >> 1; if (src[mid] < key) lo = mid + 1; else hi = mid; }
            return lo;
        };
        int a = lb(i);
        rp[i] = a;
        if (i < NN) {
            int d = lb(i + 1) - a;
            norm[i] = rsqrtf((float)(d < 1 ? 1 : d));
        }
    } else {
        int j = i - (NN + 1);
        const int n0 = HID_F * IN_F;
        const int n1 = 2 * OUT_F * HID_F;
        if (j < n0) {
            float x = W0[j];
            unsigned short hh = f2bf(x);
            W0h[j] = hh; W0l[j] = f2bf(x - bf2f(hh));
        } else if (j < n0 + n1) {
            int q = j - n0;
            int r = q / HID_F, c = q % HID_F;
            float x = (r < OUT_F) ? Wmu[r * HID_F + c] : Wls[(r - OUT_F) * HID_F + c];
            unsigned short hh = f2bf(x);
            Wch[q] = hh; Wcl[q] = f2bf(x - bf2f(hh));
        }
    }
}

// ---------- convert h*norm -> bf16 hi/lo ----------
__global__ void k_conv_h(const float* __restrict__ h, const float* __restrict__ norm,
                         unsigned short* __restrict__ hi, unsigned short* __restrict__ lo,
                         int total4) {
    int i = blockIdx.x * blockDim.x + threadIdx.x;
    if (i >= total4) return;
    int n = i / (IN_F / 4);
    float nv = norm[n];
    float4 v = reinterpret_cast<const float4*>(h)[i];
    ushort4v h4, l4;
    float x;
    x = v.x * nv; h4.x = f2bf(x); l4.x = f2bf(x - bf2f(h4.x));
    x = v.y * nv; h4.y = f2bf(x); l4.y = f2bf(x - bf2f(h4.y));
    x = v.z * nv; h4.z = f2bf(x); l4.z = f2bf(x - bf2f(h4.z));
    x = v.w * nv; h4.w = f2bf(x); l4.w = f2bf(x - bf2f(h4.w));
    reinterpret_cast<ushort4v*>(hi)[i] = h4;
    reinterpret_cast<ushort4v*>(lo)[i] = l4;
}

// ---------- generic C = A*B^T, split-bf16, fp32 acc (r1/r5-proven scalar store) ----------
template <int K, int MT, int NT>
__global__ __launch_bounds__(256) void k_gemm_bt(
    const unsigned short* __restrict__ Ahi, const unsigned short* __restrict__ Alo,
    const unsigned short* __restrict__ Bhi, const unsigned short* __restrict__ Blo,
    float* __restrict__ C, int ldc) {
    const int lane = threadIdx.x & 63, wid = threadIdx.x >> 6;
    const int wr = wid >> 1, wc = wid & 1;
    const long i0 = (long)blockIdx.x * (32 * MT) + wr * (16 * MT);
    const long j0 = (long)blockIdx.y * (32 * NT) + wc * (16 * NT);
    const int rl = lane & 15, kq = lane >> 4;
    f32x4 acc[MT][NT] = {};
    for (int kc = 0; kc < K; kc += 32) {
        const int kb = kc + kq * 8;
        short8v ah[MT], al[MT], bh[NT], bl[NT];
#pragma unroll
        for (int m = 0; m < MT; ++m) {
            size_t off = (size_t)(i0 + m * 16 + rl) * K + kb;
            ah[m] = *reinterpret_cast<const short8v*>(Ahi + off);
            al[m] = *reinterpret_cast<const short8v*>(Alo + off);
        }
#pragma unroll
        for (int n = 0; n < NT; ++n) {
            size_t off = (size_t)(j0 + n * 16 + rl) * K + kb;
            bh[n] = *reinterpret_cast<const short8v*>(Bhi + off);
            bl[n] = *reinterpret_cast<const short8v*>(Blo + off);
        }
#pragma unroll
        for (int m = 0; m < MT; ++m)
#pragma unroll
            for (int n = 0; n < NT; ++n) {
                acc[m][n] = __builtin_amdgcn_mfma_f32_16x16x32_bf16(ah[m], bh[n], acc[m][n], 0, 0, 0);
                acc[m][n] = __builtin_amdgcn_mfma_f32_16x16x32_bf16(ah[m], bl[n], acc[m][n], 0, 0, 0);
                acc[m][n] = __builtin_amdgcn_mfma_f32_16x16x32_bf16(al[m], bh[n], acc[m][n], 0, 0, 0);
            }
    }
    const int crow = (lane >> 4) * 4;
#pragma unroll
    for (int m = 0; m < MT; ++m)
#pragma unroll
        for (int n = 0; n < NT; ++n) {
            size_t base = (size_t)(i0 + m * 16 + crow) * ldc + (size_t)(j0 + n * 16 + rl);
#pragma unroll
            for (int r = 0; r < 4; ++r)
                C[base + (size_t)r * ldc] = acc[m][n][r];
        }
}

// ---------- SpMM1 (r1/r5-proven scalar): h1p = relu(segsum(X1[dst])*norm)*norm ----------
__global__ __launch_bounds__(128) void k_spmm1(
    const float* __restrict__ X, const int* __restrict__ rp, const int* __restrict__ dst,
    const float* __restrict__ norm, float* __restrict__ h1p) {
    int n = blockIdx.x;
    int t = threadIdx.x;
    int e0 = rp[n], e1 = rp[n + 1];
    float acc = 0.f;
    int e = e0;
    for (; e + 4 <= e1; e += 4) {
        int d0 = dst[e] * HID_F, d1 = dst[e + 1] * HID_F;
        int d2 = dst[e + 2] * HID_F, d3 = dst[e + 3] * HID_F;
        acc += X[d0 + t];
        acc += X[d1 + t];
        acc += X[d2 + t];
        acc += X[d3 + t];
    }
    for (; e < e1; ++e) acc += X[dst[e] * HID_F + t];
    float nv = norm[n];
    float v = acc * nv;
    v = v > 0.f ? v : 0.f;
    h1p[n * HID_F + t] = v * nv;
}

// ---------- SpMM2 (r1/r5-proven scalar): agg = segsum(h1p[dst]) -> bf16 hi/lo ----------
__global__ __launch_bounds__(128) void k_spmm2(
    const float* __restrict__ X, const int* __restrict__ rp, const int* __restrict__ dst,
    unsigned short* __restrict__ hi, unsigned short* __restrict__ lo) {
    int n = blockIdx.x;
    int t = threadIdx.x;
    int e0 = rp[n], e1 = rp[n + 1];
    float acc = 0.f;
    int e = e0;
    for (; e + 4 <= e1; e += 4) {
        int d0 = dst[e] * HID_F, d1 = dst[e + 1] * HID_F;
        int d2 = dst[e + 2] * HID_F, d3 = dst[e + 3] * HID_F;
        acc += X[d0 + t];
        acc += X[d1 + t];
        acc += X[d2 + t];
        acc += X[d3 + t];
    }
    for (; e < e1; ++e) acc += X[dst[e] * HID_F + t];
    unsigned short hh = f2bf(acc);
    hi[n * HID_F + t] = hh;
    lo[n * HID_F + t] = f2bf(acc - bf2f(hh));
}

// ---------- GEMM2 + z epilogue (passed r2/r4/r5) ----------
__global__ __launch_bounds__(256) void k_gemm2z(
    const unsigned short* __restrict__ Ah16, const unsigned short* __restrict__ Al16,
    const unsigned short* __restrict__ Bh16, const unsigned short* __restrict__ Bl16,
    const float* __restrict__ norm, const float* __restrict__ eps,
    unsigned short* __restrict__ Zh, unsigned short* __restrict__ Zl) {
    const int lane = threadIdx.x & 63, wid = threadIdx.x >> 6;
    const int wr = wid >> 1, wc = wid & 1;
    const int R0 = blockIdx.x * 64;
    const int rl = lane & 15, kq = lane >> 4;
    f32x4 acc[2][4] = {};
    for (int kc = 0; kc < HID_F; kc += 32) {
        const int kb = kc + kq * 8;
        short8v ah[2], al[2], bh[4], bl[4];
#pragma unroll
        for (int m = 0; m < 2; ++m) {
            size_t off = (size_t)(R0 + wr * 32 + m * 16 + rl) * HID_F + kb;
            ah[m] = *reinterpret_cast<const short8v*>(Ah16 + off);
            al[m] = *reinterpret_cast<const short8v*>(Al16 + off);
        }
#pragma unroll
        for (int n = 0; n < 4; ++n) {
            size_t off = (size_t)(wc * 64 + n * 16 + rl) * HID_F + kb;
            bh[n] = *reinterpret_cast<const short8v*>(Bh16 + off);
            bl[n] = *reinterpret_cast<const short8v*>(Bl16 + off);
        }
#pragma unroll
        for (int m = 0; m < 2; ++m)
#pragma unroll
            for (int n = 0; n < 4; ++n) {
                acc[m][n] = __builtin_amdgcn_mfma_f32_16x16x32_bf16(ah[m], bh[n], acc[m][n], 0, 0, 0);
                acc[m][n] = __builtin_amdgcn_mfma_f32_16x16x32_bf16(ah[m], bl[n], acc[m][n], 0, 0, 0);
                acc[m][n] = __builtin_amdgcn_mfma_f32_16x16x32_bf16(al[m], bh[n], acc[m][n], 0, 0, 0);
            }
    }
    __shared__ __align__(16) float Pl[64][132];
#pragma unroll
    for (int m = 0; m < 2; ++m)
#pragma unroll
        for (int n = 0; n < 4; ++n)
#pragma unroll
            for (int r = 0; r < 4; ++r)
                Pl[wr * 32 + m * 16 + 4 * kq + r][wc * 64 + n * 16 + rl] = acc[m][n][r];
    __syncthreads();
    const int fg = threadIdx.x & 15;
    const int rr = threadIdx.x >> 4;
#pragma unroll
    for (int p = 0; p < 4; ++p) {
        int rloc = p * 16 + rr;
        int row = R0 + rloc;
        float nv = norm[row];
        f32x4 mu = *reinterpret_cast<const f32x4*>(&Pl[rloc][4 * fg]);
        f32x4 ls = *reinterpret_cast<const f32x4*>(&Pl[rloc][64 + 4 * fg]);
        f32x4 ev = *reinterpret_cast<const f32x4*>(eps + (size_t)row * OUT_F + 4 * fg);
        ushort4v zh, zl;
#pragma unroll
        for (int q = 0; q < 4; ++q) {
            float z = mu[q] * nv + expf(ls[q] * nv) * ev[q];
            unsigned short hh = f2bf(z);
            zh[q] = hh;
            zl[q] = f2bf(z - bf2f(hh));
        }
        *reinterpret_cast<ushort4v*>(Zh + (size_t)row * OUT_F + 4 * fg) = zh;
        *reinterpret_cast<ushort4v*>(Zl + (size_t)row * OUT_F + 4 * fg) = zl;
    }
}

extern "C" void kernel_launch(void* const* d_in, const int* in_sizes, int n_in,
                              void* d_out, int out_size, void* d_ws, size_t ws_size,
                              hipStream_t stream) {
    const float* h   = (const float*)d_in[0];
    const float* W0  = (const float*)d_in[1];
    const float* Wmu = (const float*)d_in[2];
    const float* Wls = (const float*)d_in[3];
    const float* eps = (const float*)d_in[4];
    const int* esrc  = (const int*)d_in[5];
    const int* edst  = (const int*)d_in[6];

    char* w = (char*)d_ws;
    auto alloc = [&](size_t bytes) {
        char* p = w;
        w += (bytes + 511) & ~(size_t)511;
        return p;
    };
    int* rp             = (int*)alloc((NN + 1) * sizeof(int));
    float* norm         = (float*)alloc(NN * sizeof(float));
    unsigned short* W0h = (unsigned short*)alloc(HID_F * IN_F * 2);
    unsigned short* W0l = (unsigned short*)alloc(HID_F * IN_F * 2);
    unsigned short* Wch = (unsigned short*)alloc(2 * OUT_F * HID_F * 2);
    unsigned short* Wcl = (unsigned short*)alloc(2 * OUT_F * HID_F * 2);
    unsigned short* Hh  = (unsigned short*)alloc((size_t)NN * IN_F * 2);
    unsigned short* Hl  = (unsigned short*)alloc((size_t)NN * IN_F * 2);
    float* X1           = (float*)alloc((size_t)NN * HID_F * sizeof(float));
    float* h1p          = (float*)alloc((size_t)NN * HID_F * sizeof(float));
    unsigned short* Agh = (unsigned short*)alloc((size_t)NN * HID_F * 2);
    unsigned short* Agl = (unsigned short*)alloc((size_t)NN * HID_F * 2);
    unsigned short* Zh  = (unsigned short*)alloc((size_t)NN * OUT_F * 2);
    unsigned short* Zl  = (unsigned short*)alloc((size_t)NN * OUT_F * 2);

    const int prep_threads = (NN + 1) + HID_F * IN_F + 2 * OUT_F * HID_F;
    k_prep<<<(prep_threads + 255) / 256, 256, 0, stream>>>(
        esrc, W0, Wmu, Wls, rp, norm, W0h, W0l, Wch, Wcl);

    k_conv_h<<<((NN * IN_F / 4) + 255) / 256, 256, 0, stream>>>(h, norm, Hh, Hl, NN * IN_F / 4);

    // X1 = (h*norm) @ W0^T
    k_gemm_bt<IN_F, 2, 2><<<dim3(NN / 64, HID_F / 64), 256, 0, stream>>>(
        Hh, Hl, W0h, W0l, X1, HID_F);

    k_spmm1<<<NN, 128, 0, stream>>>(X1, rp, edst, norm, h1p);
    k_spmm2<<<NN, 128, 0, stream>>>(h1p, rp, edst, Agh, Agl);

    k_gemm2z<<<NN / 64, 256, 0, stream>>>(Agh, Agl, Wch, Wcl, norm, eps, Zh, Zl);

    // PROBE ROUND: launch gemm3 three times (idempotent, deterministic).
    // dur_us - 141.1 = 2 * t(gemm3). Do not keep beyond this round.
    k_gemm_bt<OUT_F, 4, 4><<<dim3(NN / 128, NN / 128), 256, 0, stream>>>(
        Zh, Zl, Zh, Zl, (float*)d_out, NN);
    k_gemm_bt<OUT_F, 4, 4><<<dim3(NN / 128, NN / 128), 256, 0, stream>>>(
        Zh, Zl, Zh, Zl, (float*)d_out, NN);
    k_gemm_bt<OUT_F, 4, 4><<<dim3(NN / 128, NN / 128), 256, 0, stream>>>(
        Zh, Zl, Zh, Zl, (float*)d_out, NN);
}

// Round 10
// 138.636 us; speedup vs baseline: 2.1162x; 2.1162x over previous
//
#include <hip/hip_runtime.h>
#include <hip/hip_bf16.h>
#include <cstdint>
#include <cstddef>

#define NN 8192
#define EE 262144
#define IN_F 256
#define HID_F 128
#define OUT_F 64

typedef __attribute__((ext_vector_type(8))) short short8v;
typedef __attribute__((ext_vector_type(4))) float f32x4;
typedef __attribute__((ext_vector_type(4))) unsigned short ushort4v;

// bf16 round-to-nearest-even split helpers
static __device__ __forceinline__ unsigned short f2bf(float x) {
    unsigned int u = __float_as_uint(x);
    unsigned int r = (u + 0x7fffu + ((u >> 16) & 1u)) >> 16;
    return (unsigned short)r;
}
static __device__ __forceinline__ float bf2f(unsigned short u) {
    return __uint_as_float(((unsigned int)u) << 16);
}

// ---------- prep: rowptr (binary search on sorted src) + norm + weight conversion ----------
__global__ void k_prep(const int* __restrict__ src,
                       const float* __restrict__ W0, const float* __restrict__ Wmu,
                       const float* __restrict__ Wls,
                       int* __restrict__ rp, float* __restrict__ norm,
                       unsigned short* __restrict__ W0h, unsigned short* __restrict__ W0l,
                       unsigned short* __restrict__ Wch, unsigned short* __restrict__ Wcl) {
    int i = blockIdx.x * blockDim.x + threadIdx.x;
    if (i <= NN) {
        auto lb = [&](int key) {
            int lo = 0, hi = EE;
            while (lo < hi) { int mid = (lo + hi) >> 1; if (src[mid] < key) lo = mid + 1; else hi = mid; }
            return lo;
        };
        int a = lb(i);
        rp[i] = a;
        if (i < NN) {
            int d = lb(i + 1) - a;
            norm[i] = rsqrtf((float)(d < 1 ? 1 : d));
        }
    } else {
        int j = i - (NN + 1);
        const int n0 = HID_F * IN_F;
        const int n1 = 2 * OUT_F * HID_F;
        if (j < n0) {
            float x = W0[j];
            unsigned short hh = f2bf(x);
            W0h[j] = hh; W0l[j] = f2bf(x - bf2f(hh));
        } else if (j < n0 + n1) {
            int q = j - n0;
            int r = q / HID_F, c = q % HID_F;
            float x = (r < OUT_F) ? Wmu[r * HID_F + c] : Wls[(r - OUT_F) * HID_F + c];
            unsigned short hh = f2bf(x);
            Wch[q] = hh; Wcl[q] = f2bf(x - bf2f(hh));
        }
    }
}

// ---------- convert h*norm -> bf16 hi/lo ----------
__global__ void k_conv_h(const float* __restrict__ h, const float* __restrict__ norm,
                         unsigned short* __restrict__ hi, unsigned short* __restrict__ lo,
                         int total4) {
    int i = blockIdx.x * blockDim.x + threadIdx.x;
    if (i >= total4) return;
    int n = i / (IN_F / 4);
    float nv = norm[n];
    float4 v = reinterpret_cast<const float4*>(h)[i];
    ushort4v h4, l4;
    float x;
    x = v.x * nv; h4.x = f2bf(x); l4.x = f2bf(x - bf2f(h4.x));
    x = v.y * nv; h4.y = f2bf(x); l4.y = f2bf(x - bf2f(h4.y));
    x = v.z * nv; h4.z = f2bf(x); l4.z = f2bf(x - bf2f(h4.z));
    x = v.w * nv; h4.w = f2bf(x); l4.w = f2bf(x - bf2f(h4.w));
    reinterpret_cast<ushort4v*>(hi)[i] = h4;
    reinterpret_cast<ushort4v*>(lo)[i] = l4;
}

// ---------- generic C = A*B^T, split-bf16, fp32 acc (r1/r5-proven scalar store) ----------
template <int K, int MT, int NT>
__global__ __launch_bounds__(256) void k_gemm_bt(
    const unsigned short* __restrict__ Ahi, const unsigned short* __restrict__ Alo,
    const unsigned short* __restrict__ Bhi, const unsigned short* __restrict__ Blo,
    float* __restrict__ C, int ldc) {
    const int lane = threadIdx.x & 63, wid = threadIdx.x >> 6;
    const int wr = wid >> 1, wc = wid & 1;
    const long i0 = (long)blockIdx.x * (32 * MT) + wr * (16 * MT);
    const long j0 = (long)blockIdx.y * (32 * NT) + wc * (16 * NT);
    const int rl = lane & 15, kq = lane >> 4;
    f32x4 acc[MT][NT] = {};
    for (int kc = 0; kc < K; kc += 32) {
        const int kb = kc + kq * 8;
        short8v ah[MT], al[MT], bh[NT], bl[NT];
#pragma unroll
        for (int m = 0; m < MT; ++m) {
            size_t off = (size_t)(i0 + m * 16 + rl) * K + kb;
            ah[m] = *reinterpret_cast<const short8v*>(Ahi + off);
            al[m] = *reinterpret_cast<const short8v*>(Alo + off);
        }
#pragma unroll
        for (int n = 0; n < NT; ++n) {
            size_t off = (size_t)(j0 + n * 16 + rl) * K + kb;
            bh[n] = *reinterpret_cast<const short8v*>(Bhi + off);
            bl[n] = *reinterpret_cast<const short8v*>(Blo + off);
        }
#pragma unroll
        for (int m = 0; m < MT; ++m)
#pragma unroll
            for (int n = 0; n < NT; ++n) {
                acc[m][n] = __builtin_amdgcn_mfma_f32_16x16x32_bf16(ah[m], bh[n], acc[m][n], 0, 0, 0);
                acc[m][n] = __builtin_amdgcn_mfma_f32_16x16x32_bf16(ah[m], bl[n], acc[m][n], 0, 0, 0);
                acc[m][n] = __builtin_amdgcn_mfma_f32_16x16x32_bf16(al[m], bh[n], acc[m][n], 0, 0, 0);
            }
    }
    const int crow = (lane >> 4) * 4;
#pragma unroll
    for (int m = 0; m < MT; ++m)
#pragma unroll
        for (int n = 0; n < NT; ++n) {
            size_t base = (size_t)(i0 + m * 16 + crow) * ldc + (size_t)(j0 + n * 16 + rl);
#pragma unroll
            for (int r = 0; r < 4; ++r)
                C[base + (size_t)r * ldc] = acc[m][n][r];
        }
}

// ---------- SpMM1 (r1/r5-proven scalar): h1p = relu(segsum(X1[dst])*norm)*norm ----------
__global__ __launch_bounds__(128) void k_spmm1(
    const float* __restrict__ X, const int* __restrict__ rp, const int* __restrict__ dst,
    const float* __restrict__ norm, float* __restrict__ h1p) {
    int n = blockIdx.x;
    int t = threadIdx.x;
    int e0 = rp[n], e1 = rp[n + 1];
    float acc = 0.f;
    int e = e0;
    for (; e + 4 <= e1; e += 4) {
        int d0 = dst[e] * HID_F, d1 = dst[e + 1] * HID_F;
        int d2 = dst[e + 2] * HID_F, d3 = dst[e + 3] * HID_F;
        acc += X[d0 + t];
        acc += X[d1 + t];
        acc += X[d2 + t];
        acc += X[d3 + t];
    }
    for (; e < e1; ++e) acc += X[dst[e] * HID_F + t];
    float nv = norm[n];
    float v = acc * nv;
    v = v > 0.f ? v : 0.f;
    h1p[n * HID_F + t] = v * nv;
}

// ---------- SpMM2 (r1/r5-proven scalar): agg = segsum(h1p[dst]) -> bf16 hi/lo ----------
__global__ __launch_bounds__(128) void k_spmm2(
    const float* __restrict__ X, const int* __restrict__ rp, const int* __restrict__ dst,
    unsigned short* __restrict__ hi, unsigned short* __restrict__ lo) {
    int n = blockIdx.x;
    int t = threadIdx.x;
    int e0 = rp[n], e1 = rp[n + 1];
    float acc = 0.f;
    int e = e0;
    for (; e + 4 <= e1; e += 4) {
        int d0 = dst[e] * HID_F, d1 = dst[e + 1] * HID_F;
        int d2 = dst[e + 2] * HID_F, d3 = dst[e + 3] * HID_F;
        acc += X[d0 + t];
        acc += X[d1 + t];
        acc += X[d2 + t];
        acc += X[d3 + t];
    }
    for (; e < e1; ++e) acc += X[dst[e] * HID_F + t];
    unsigned short hh = f2bf(acc);
    hi[n * HID_F + t] = hh;
    lo[n * HID_F + t] = f2bf(acc - bf2f(hh));
}

// ---------- GEMM2 + z epilogue (passed r2/r4/r5) ----------
__global__ __launch_bounds__(256) void k_gemm2z(
    const unsigned short* __restrict__ Ah16, const unsigned short* __restrict__ Al16,
    const unsigned short* __restrict__ Bh16, const unsigned short* __restrict__ Bl16,
    const float* __restrict__ norm, const float* __restrict__ eps,
    unsigned short* __restrict__ Zh, unsigned short* __restrict__ Zl) {
    const int lane = threadIdx.x & 63, wid = threadIdx.x >> 6;
    const int wr = wid >> 1, wc = wid & 1;
    const int R0 = blockIdx.x * 64;
    const int rl = lane & 15, kq = lane >> 4;
    f32x4 acc[2][4] = {};
    for (int kc = 0; kc < HID_F; kc += 32) {
        const int kb = kc + kq * 8;
        short8v ah[2], al[2], bh[4], bl[4];
#pragma unroll
        for (int m = 0; m < 2; ++m) {
            size_t off = (size_t)(R0 + wr * 32 + m * 16 + rl) * HID_F + kb;
            ah[m] = *reinterpret_cast<const short8v*>(Ah16 + off);
            al[m] = *reinterpret_cast<const short8v*>(Al16 + off);
        }
#pragma unroll
        for (int n = 0; n < 4; ++n) {
            size_t off = (size_t)(wc * 64 + n * 16 + rl) * HID_F + kb;
            bh[n] = *reinterpret_cast<const short8v*>(Bh16 + off);
            bl[n] = *reinterpret_cast<const short8v*>(Bl16 + off);
        }
#pragma unroll
        for (int m = 0; m < 2; ++m)
#pragma unroll
            for (int n = 0; n < 4; ++n) {
                acc[m][n] = __builtin_amdgcn_mfma_f32_16x16x32_bf16(ah[m], bh[n], acc[m][n], 0, 0, 0);
                acc[m][n] = __builtin_amdgcn_mfma_f32_16x16x32_bf16(ah[m], bl[n], acc[m][n], 0, 0, 0);
                acc[m][n] = __builtin_amdgcn_mfma_f32_16x16x32_bf16(al[m], bh[n], acc[m][n], 0, 0, 0);
            }
    }
    __shared__ __align__(16) float Pl[64][132];
#pragma unroll
    for (int m = 0; m < 2; ++m)
#pragma unroll
        for (int n = 0; n < 4; ++n)
#pragma unroll
            for (int r = 0; r < 4; ++r)
                Pl[wr * 32 + m * 16 + 4 * kq + r][wc * 64 + n * 16 + rl] = acc[m][n][r];
    __syncthreads();
    const int fg = threadIdx.x & 15;
    const int rr = threadIdx.x >> 4;
#pragma unroll
    for (int p = 0; p < 4; ++p) {
        int rloc = p * 16 + rr;
        int row = R0 + rloc;
        float nv = norm[row];
        f32x4 mu = *reinterpret_cast<const f32x4*>(&Pl[rloc][4 * fg]);
        f32x4 ls = *reinterpret_cast<const f32x4*>(&Pl[rloc][64 + 4 * fg]);
        f32x4 ev = *reinterpret_cast<const f32x4*>(eps + (size_t)row * OUT_F + 4 * fg);
        ushort4v zh, zl;
#pragma unroll
        for (int q = 0; q < 4; ++q) {
            float z = mu[q] * nv + expf(ls[q] * nv) * ev[q];
            unsigned short hh = f2bf(z);
            zh[q] = hh;
            zl[q] = f2bf(z - bf2f(hh));
        }
        *reinterpret_cast<ushort4v*>(Zh + (size_t)row * OUT_F + 4 * fg) = zh;
        *reinterpret_cast<ushort4v*>(Zl + (size_t)row * OUT_F + 4 * fg) = zl;
    }
}

// ---------- GEMM3: logits = z @ z^T with LDS-staged, fully-coalesced epilogue ----------
// Same math/values as r5. Epilogue: per m-quarter, stage 32x128 fp32 tile in LDS,
// then 256 threads copy out f32x4 chunks so each wave-store covers 2x512B
// contiguous row segments (4 full 128B lines each). 16 store instrs/thread vs 64.
__global__ __launch_bounds__(256) void k_gemm3(
    const unsigned short* __restrict__ Zh, const unsigned short* __restrict__ Zl,
    float* __restrict__ C) {
    const int lane = threadIdx.x & 63, wid = threadIdx.x >> 6;
    const int wr = wid >> 1, wc = wid & 1;
    const long i0 = (long)blockIdx.x * 128 + wr * 64;
    const long j0 = (long)blockIdx.y * 128 + wc * 64;
    const int rl = lane & 15, kq = lane >> 4;
    f32x4 acc[4][4] = {};
    for (int kc = 0; kc < OUT_F; kc += 32) {
        const int kb = kc + kq * 8;
        short8v ah[4], al[4], bh[4], bl[4];
#pragma unroll
        for (int m = 0; m < 4; ++m) {
            size_t off = (size_t)(i0 + m * 16 + rl) * OUT_F + kb;
            ah[m] = *reinterpret_cast<const short8v*>(Zh + off);
            al[m] = *reinterpret_cast<const short8v*>(Zl + off);
        }
#pragma unroll
        for (int n = 0; n < 4; ++n) {
            size_t off = (size_t)(j0 + n * 16 + rl) * OUT_F + kb;
            bh[n] = *reinterpret_cast<const short8v*>(Zh + off);
            bl[n] = *reinterpret_cast<const short8v*>(Zl + off);
        }
#pragma unroll
        for (int m = 0; m < 4; ++m)
#pragma unroll
            for (int n = 0; n < 4; ++n) {
                acc[m][n] = __builtin_amdgcn_mfma_f32_16x16x32_bf16(ah[m], bh[n], acc[m][n], 0, 0, 0);
                acc[m][n] = __builtin_amdgcn_mfma_f32_16x16x32_bf16(ah[m], bl[n], acc[m][n], 0, 0, 0);
                acc[m][n] = __builtin_amdgcn_mfma_f32_16x16x32_bf16(al[m], bh[n], acc[m][n], 0, 0, 0);
            }
    }
    __shared__ __align__(16) float Cl[32][132];
    const long rowbase = (long)blockIdx.x * 128;
    const long colbase = (long)blockIdx.y * 128;
#pragma unroll
    for (int m = 0; m < 4; ++m) {
        if (m) __syncthreads();
#pragma unroll
        for (int n = 0; n < 4; ++n)
#pragma unroll
            for (int r = 0; r < 4; ++r)
                Cl[wr * 16 + 4 * kq + r][wc * 64 + n * 16 + rl] = acc[m][n][r];
        __syncthreads();
#pragma unroll
        for (int k = 0; k < 4; ++k) {
            int idx = threadIdx.x + k * 256;
            int lr = idx >> 5;
            int lc4 = (idx & 31) * 4;
            long grow = rowbase + (lr >> 4) * 64 + m * 16 + (lr & 15);
            *reinterpret_cast<f32x4*>(C + grow * NN + colbase + lc4) =
                *reinterpret_cast<const f32x4*>(&Cl[lr][lc4]);
        }
    }
}

extern "C" void kernel_launch(void* const* d_in, const int* in_sizes, int n_in,
                              void* d_out, int out_size, void* d_ws, size_t ws_size,
                              hipStream_t stream) {
    const float* h   = (const float*)d_in[0];
    const float* W0  = (const float*)d_in[1];
    const float* Wmu = (const float*)d_in[2];
    const float* Wls = (const float*)d_in[3];
    const float* eps = (const float*)d_in[4];
    const int* esrc  = (const int*)d_in[5];
    const int* edst  = (const int*)d_in[6];

    char* w = (char*)d_ws;
    auto alloc = [&](size_t bytes) {
        char* p = w;
        w += (bytes + 511) & ~(size_t)511;
        return p;
    };
    int* rp             = (int*)alloc((NN + 1) * sizeof(int));
    float* norm         = (float*)alloc(NN * sizeof(float));
    unsigned short* W0h = (unsigned short*)alloc(HID_F * IN_F * 2);
    unsigned short* W0l = (unsigned short*)alloc(HID_F * IN_F * 2);
    unsigned short* Wch = (unsigned short*)alloc(2 * OUT_F * HID_F * 2);
    unsigned short* Wcl = (unsigned short*)alloc(2 * OUT_F * HID_F * 2);
    unsigned short* Hh  = (unsigned short*)alloc((size_t)NN * IN_F * 2);
    unsigned short* Hl  = (unsigned short*)alloc((size_t)NN * IN_F * 2);
    float* X1           = (float*)alloc((size_t)NN * HID_F * sizeof(float));
    float* h1p          = (float*)alloc((size_t)NN * HID_F * sizeof(float));
    unsigned short* Agh = (unsigned short*)alloc((size_t)NN * HID_F * 2);
    unsigned short* Agl = (unsigned short*)alloc((size_t)NN * HID_F * 2);
    unsigned short* Zh  = (unsigned short*)alloc((size_t)NN * OUT_F * 2);
    unsigned short* Zl  = (unsigned short*)alloc((size_t)NN * OUT_F * 2);

    const int prep_threads = (NN + 1) + HID_F * IN_F + 2 * OUT_F * HID_F;
    k_prep<<<(prep_threads + 255) / 256, 256, 0, stream>>>(
        esrc, W0, Wmu, Wls, rp, norm, W0h, W0l, Wch, Wcl);

    k_conv_h<<<((NN * IN_F / 4) + 255) / 256, 256, 0, stream>>>(h, norm, Hh, Hl, NN * IN_F / 4);

    // X1 = (h*norm) @ W0^T
    k_gemm_bt<IN_F, 2, 2><<<dim3(NN / 64, HID_F / 64), 256, 0, stream>>>(
        Hh, Hl, W0h, W0l, X1, HID_F);

    k_spmm1<<<NN, 128, 0, stream>>>(X1, rp, edst, norm, h1p);
    k_spmm2<<<NN, 128, 0, stream>>>(h1p, rp, edst, Agh, Agl);

    k_gemm2z<<<NN / 64, 256, 0, stream>>>(Agh, Agl, Wch, Wcl, norm, eps, Zh, Zl);

    // logits = z @ z^T  (LDS-staged coalesced stores)
    k_gemm3<<<dim3(NN / 128, NN / 128), 256, 0, stream>>>(Zh, Zl, (float*)d_out);
}